// Round 2
// baseline (347.959 us; speedup 1.0000x reference)
//
#include <hip/hip_runtime.h>
#include <math.h>

#define B 64
#define V 64
#define NN 16384
#define RR 32
#define HIDN 128
#define BIGV 1000000000.0f
#define CAP 4096   // survivor-list capacity; actual K ~0-16 (<=512 if an action is a stop)

// One block per batch row b, 512 threads. Fully fused:
//   phase 1: stream row0 + (<=t) action rows of tables (int4 coalesced),
//            compact surviving n's into an LDS list (LDS atomicAdd).
//   phase 2: wave 0, thread v: gather tables[b,v,n] for the K survivors,
//            build counts[r][v] (u32) and sigma-presence masks mask[r][v]
//            (Y=32 fits one word; uniq = popc). Layout [r][V]: bank = v%32,
//            2-way aliasing per wave64 access = free.
//   phase 3: features per (b,v); stop column from OR_r mask[r][0] (= OR over
//            survivors of 1<<sigma[n], since each survivor hits exactly one r).
//   phase 4: threads 0..64: fused 2->128->1 MLP, exact GELU via erff.
__global__ __launch_bounds__(512)
void k_fused(const int* __restrict__ tables,
             const int* __restrict__ sigma,
             const int* __restrict__ base_obs,
             const int* __restrict__ actions,
             const int* __restrict__ responses,
             const int* __restrict__ t_ptr,
             const float* __restrict__ W1,
             const float* __restrict__ b1,
             const float* __restrict__ W2,
             const float* __restrict__ b2,
             float* __restrict__ out,
             int T)
{
    const int b = blockIdx.x;
    const int tid = threadIdx.x;

    __shared__ int s_cnt;
    __shared__ int s_list[CAP];
    __shared__ unsigned s_counts[RR * V];
    __shared__ unsigned s_mask[RR * V];
    __shared__ float s_feat[(V + 1) * 2];

    if (tid == 0) s_cnt = 0;
    for (int i = tid; i < RR * V; i += 512) { s_counts[i] = 0u; s_mask[i] = 0u; }
    __syncthreads();

    const int t = t_ptr[0];
    const int base = base_obs[b];
    const int* row0 = tables + (size_t)b * V * NN;

    // ---- phase 1: scan + compact (NN/(512*4) = 8 sweeps) ----
    for (int n0 = tid * 4; n0 < NN; n0 += 512 * 4) {
        const int4 tv = *(const int4*)(row0 + n0);
        int m0 = (tv.x == base), m1 = (tv.y == base), m2 = (tv.z == base), m3 = (tv.w == base);
        for (int i = 0; i < t; ++i) {
            const int a = actions[b * T + i];     // uniform, L1-hit, hoistable
            if (a == V) continue;                 // stop: m unchanged (uniform branch)
            const int resp = responses[b * T + i];
            const int4 lv = *(const int4*)(row0 + a * NN + n0);
            m0 &= (lv.x == resp); m1 &= (lv.y == resp); m2 &= (lv.z == resp); m3 &= (lv.w == resp);
        }
        if (m0) { int i = atomicAdd(&s_cnt, 1); if (i < CAP) s_list[i] = n0; }
        if (m1) { int i = atomicAdd(&s_cnt, 1); if (i < CAP) s_list[i] = n0 + 1; }
        if (m2) { int i = atomicAdd(&s_cnt, 1); if (i < CAP) s_list[i] = n0 + 2; }
        if (m3) { int i = atomicAdd(&s_cnt, 1); if (i < CAP) s_list[i] = n0 + 3; }
    }
    __syncthreads();

    const int K = min(s_cnt, CAP);
    const int* bsig = sigma + (size_t)b * NN;

    // ---- phase 2: per-cell histograms over the K survivors ----
    if (tid < V) {
        const int v = tid;
        const int* rowv = row0 + v * NN;
        for (int k = 0; k < K; ++k) {
            const int n = s_list[k];              // LDS, uniform per k
            const int r = rowv[n];                // gather: 64 lines, indep across k
            const int y = bsig[n];                // same addr all lanes: broadcast
            s_counts[r * V + v] += 1u;            // thread v owns column v: no race
            s_mask[r * V + v] |= (1u << y);
        }
    }
    __syncthreads();

    // ---- phase 3: features ----
    if (tid < V) {
        const int v = tid;
        const float safe = (K > 0) ? (float)K : 1.0f;
        float sz = 0.f, amb = 0.f;
        unsigned pm = 0u;
        for (int r = 0; r < RR; ++r) {
            const unsigned mk = s_mask[r * V + v];
            const float c = (float)s_counts[r * V + v];
            pm |= mk;
            sz += c * c;
            amb += c * (float)__popc(mk);
        }
        sz /= safe; amb /= safe;
        bool forb = (v == 0);
        for (int i = 0; i < t; ++i)
            if (actions[b * T + i] == v) forb = true;  // a==V never matches v<64
        if (forb) { sz = BIGV; amb = BIGV; }
        s_feat[v * 2 + 0] = amb;
        s_feat[v * 2 + 1] = sz;
        if (v == 0) {                              // stop column
            s_feat[V * 2 + 0] = (float)__popc(pm); // stop_amb = popc(OR_r mask[r][0])
            s_feat[V * 2 + 1] = (float)K;          // total0
        }
    }
    __syncthreads();

    // ---- phase 4: fused MLP (2 -> 128 -> 1), exact GELU ----
    if (tid <= V) {
        float f0 = 0.f, f1 = 0.f;
        if (K > 0) { f0 = s_feat[tid * 2 + 0]; f1 = s_feat[tid * 2 + 1]; }
        float acc = b2[0];
        for (int j = 0; j < HIDN; ++j) {
            const float x = f0 * W1[j] + f1 * W1[HIDN + j] + b1[j];
            const float g = 0.5f * x * (1.0f + erff(x * 0.70710678118654752f));
            acc = fmaf(g, W2[j], acc);
        }
        out[b * (V + 1) + tid] = acc;
    }
}

extern "C" void kernel_launch(void* const* d_in, const int* in_sizes, int n_in,
                              void* d_out, int out_size, void* d_ws, size_t ws_size,
                              hipStream_t stream) {
    const int* tables    = (const int*)d_in[0];
    const int* sigma     = (const int*)d_in[1];
    const int* base_obs  = (const int*)d_in[2];
    const int* actions   = (const int*)d_in[3];
    const int* responses = (const int*)d_in[4];
    const float* W1      = (const float*)d_in[5];
    const float* b1      = (const float*)d_in[6];
    const float* W2      = (const float*)d_in[7];
    const float* b2      = (const float*)d_in[8];
    const int* t_ptr     = (const int*)d_in[9];
    float* out = (float*)d_out;

    const int T = in_sizes[3] / B;   // actions is [B,T]

    // Single dispatch; no workspace, no memset.
    k_fused<<<B, 512, 0, stream>>>(tables, sigma, base_obs, actions, responses,
                                   t_ptr, W1, b1, W2, b2, out, T);
}

// Round 3
// 342.236 us; speedup vs baseline: 1.0167x; 1.0167x over previous
//
#include <hip/hip_runtime.h>
#include <math.h>

#define B 64
#define V 64
#define NN 16384
#define RR 32
#define HIDN 128
#define BIGV 1000000000.0f
#define NTHR 1024
#define NWAVE (NTHR / 64)

// One block per batch row b, 1024 threads (16 waves). Fully fused:
//   phase 1: stream row0 + (<=t) action rows (int4 coalesced, 4 sweeps),
//            compact surviving n's into an LDS list (LDS atomicAdd).
//   phase 2: ALL 16 waves: wave w handles k = w, w+16, ...; lane v gathers
//            tables[b,v,n] and updates counts[r][v] / sigma-presence mask[r][v]
//            via LDS atomics (lanes hit distinct v -> bank v%32, conflict-free;
//            cross-wave same-(r,v) collisions handled by the atomic).
//   phase 3: features per (b,v); stop column from OR_r mask[r][0].
//   phase 4: threads 0..64: fused 2->128->1 MLP, exact GELU via erff.
// LDS: list 64 KB + counts 8 KB + mask 8 KB + feat 0.5 KB ~= 80.6 KB -> 1 block/CU
// (grid is only 64 blocks on 256 CUs, so occupancy is grid-bound anyway).
__global__ __launch_bounds__(NTHR)
void k_fused(const int* __restrict__ tables,
             const int* __restrict__ sigma,
             const int* __restrict__ base_obs,
             const int* __restrict__ actions,
             const int* __restrict__ responses,
             const int* __restrict__ t_ptr,
             const float* __restrict__ W1,
             const float* __restrict__ b1,
             const float* __restrict__ W2,
             const float* __restrict__ b2,
             float* __restrict__ out,
             int T)
{
    const int b = blockIdx.x;
    const int tid = threadIdx.x;

    __shared__ int s_cnt;
    __shared__ int s_list[NN];                 // capacity = worst case, no clamp needed
    __shared__ unsigned s_counts[RR * V];
    __shared__ unsigned s_mask[RR * V];
    __shared__ float s_feat[(V + 1) * 2];

    if (tid == 0) s_cnt = 0;
    for (int i = tid; i < RR * V; i += NTHR) { s_counts[i] = 0u; s_mask[i] = 0u; }
    __syncthreads();

    const int t = t_ptr[0];
    const int base = base_obs[b];
    const int* row0 = tables + (size_t)b * V * NN;

    // ---- phase 1: scan + compact (NN/(NTHR*4) = 4 sweeps) ----
    for (int n0 = tid * 4; n0 < NN; n0 += NTHR * 4) {
        const int4 tv = *(const int4*)(row0 + n0);
        int m0 = (tv.x == base), m1 = (tv.y == base), m2 = (tv.z == base), m3 = (tv.w == base);
        for (int i = 0; i < t; ++i) {
            const int a = actions[b * T + i];     // uniform scalar load
            if (a == V) continue;                 // stop: m unchanged (uniform branch)
            const int resp = responses[b * T + i];
            const int4 lv = *(const int4*)(row0 + a * NN + n0);
            m0 &= (lv.x == resp); m1 &= (lv.y == resp); m2 &= (lv.z == resp); m3 &= (lv.w == resp);
        }
        if (m0) { int i = atomicAdd(&s_cnt, 1); s_list[i] = n0; }
        if (m1) { int i = atomicAdd(&s_cnt, 1); s_list[i] = n0 + 1; }
        if (m2) { int i = atomicAdd(&s_cnt, 1); s_list[i] = n0 + 2; }
        if (m3) { int i = atomicAdd(&s_cnt, 1); s_list[i] = n0 + 3; }
    }
    __syncthreads();

    const int K = s_cnt;
    const int* bsig = sigma + (size_t)b * NN;

    // ---- phase 2: per-cell histograms over the K survivors, 16-wave parallel ----
    {
        const int v = tid & 63;                  // lane
        const int w = tid >> 6;                  // wave
        const int* rowv = row0 + v * NN;
        #pragma unroll 4
        for (int k = w; k < K; k += NWAVE) {
            const int n = s_list[k];             // LDS broadcast (uniform per wave)
            const int r = rowv[n];               // 64-line gather, pipelined across k
            const int y = bsig[n];               // uniform -> scalar/broadcast
            atomicAdd(&s_counts[r * V + v], 1u); // ds_add, no return
            atomicOr(&s_mask[r * V + v], 1u << y);
        }
    }
    __syncthreads();

    // ---- phase 3: features ----
    if (tid < V) {
        const int v = tid;
        const float safe = (K > 0) ? (float)K : 1.0f;
        float sz = 0.f, amb = 0.f;
        unsigned pm = 0u;
        for (int r = 0; r < RR; ++r) {
            const unsigned mk = s_mask[r * V + v];
            const float c = (float)s_counts[r * V + v];
            pm |= mk;
            sz += c * c;
            amb += c * (float)__popc(mk);
        }
        sz /= safe; amb /= safe;
        bool forb = (v == 0);
        for (int i = 0; i < t; ++i)
            if (actions[b * T + i] == v) forb = true;  // a==V never matches v<64
        if (forb) { sz = BIGV; amb = BIGV; }
        s_feat[v * 2 + 0] = amb;
        s_feat[v * 2 + 1] = sz;
        if (v == 0) {                              // stop column
            s_feat[V * 2 + 0] = (float)__popc(pm); // stop_amb = popc(OR_r mask[r][0])
            s_feat[V * 2 + 1] = (float)K;          // total0
        }
    }
    __syncthreads();

    // ---- phase 4: fused MLP (2 -> 128 -> 1), exact GELU ----
    if (tid <= V) {
        float f0 = 0.f, f1 = 0.f;
        if (K > 0) { f0 = s_feat[tid * 2 + 0]; f1 = s_feat[tid * 2 + 1]; }
        float acc = b2[0];
        for (int j = 0; j < HIDN; ++j) {
            const float x = f0 * W1[j] + f1 * W1[HIDN + j] + b1[j];
            const float g = 0.5f * x * (1.0f + erff(x * 0.70710678118654752f));
            acc = fmaf(g, W2[j], acc);
        }
        out[b * (V + 1) + tid] = acc;
    }
}

extern "C" void kernel_launch(void* const* d_in, const int* in_sizes, int n_in,
                              void* d_out, int out_size, void* d_ws, size_t ws_size,
                              hipStream_t stream) {
    const int* tables    = (const int*)d_in[0];
    const int* sigma     = (const int*)d_in[1];
    const int* base_obs  = (const int*)d_in[2];
    const int* actions   = (const int*)d_in[3];
    const int* responses = (const int*)d_in[4];
    const float* W1      = (const float*)d_in[5];
    const float* b1      = (const float*)d_in[6];
    const float* W2      = (const float*)d_in[7];
    const float* b2      = (const float*)d_in[8];
    const int* t_ptr     = (const int*)d_in[9];
    float* out = (float*)d_out;

    const int T = in_sizes[3] / B;   // actions is [B,T]

    k_fused<<<B, NTHR, 0, stream>>>(tables, sigma, base_obs, actions, responses,
                                    t_ptr, W1, b1, W2, b2, out, T);
}